// Round 1
// baseline (413.483 us; speedup 1.0000x reference)
//
#include <hip/hip_runtime.h>
#include <math.h>

// GAT 2-layer pipeline. CSR-by-dst built per launch via LDS-staged counting
// sort into FIXED-CAPACITY buckets (16384 slots/bucket; bucket load is
// Binomial(3.3M,1/391): mean 8448, sigma 92 -> cap is +86 sigma, unreachable).
// Aggregation: atomic-free per-node online softmax, bf16 features (absmax
// ~4e-3 << 1.1e-2 threshold). Layer-1 GEMM on MFMA (bf16): h^T = W^T . x^T.
// Sizes fixed by reference: F_IN=256, HEADS=8, HID=8 -> C1=64; layer2 1x1.
//
// R(this): layer-1 aggregation feature-sliced into 4 passes of 16 features
// (= 2 heads, so softmax denoms never span passes). h1 stored slice-major
// (h1t[slice][node][16], 3.2MB/slice) + per-slice packed attention terms
// (as1t[slice][node], 0.4MB) -> per-pass gather working set 3.6MB fits the
// 4MB per-XCD L2, converting the old 224MB of scattered L2-miss traffic
// (3.1 TB/s structural rate) into L2-hit gathers + compulsory fills.
// W2 projection accumulated into h2 across passes (stream-ordered RMW).
#define FIN 256
#define C1  64
#define NH  8
#define HID 8
#define MAXBUK 512        // buckets of 256 nodes; N=100000 -> 391 buckets
#define CAPLOG 14         // fixed bucket capacity 16384 edges
#define SC_CHUNK 8192     // edges per k_bscatter block (512 thr, EPT 16)
#define EPT (SC_CHUNK / 512)
#define WT_STRIDE 264     // 256 k + 8 pad (bf16 units)

typedef unsigned short ushort_t;
typedef unsigned int uint_t;
typedef __attribute__((ext_vector_type(8))) short short8;   // 8 x bf16 MFMA frag
typedef __attribute__((ext_vector_type(4))) float f32x4;    // MFMA acc

__device__ __forceinline__ ushort_t f2bf(float f) {   // round-to-nearest-even
    uint_t u = __float_as_uint(f);
    u += 0x7fffu + ((u >> 16) & 1u);
    return (ushort_t)(u >> 16);
}
__device__ __forceinline__ uint_t packbf2(float lo, float hi) {
    return (uint_t)f2bf(lo) | ((uint_t)f2bf(hi) << 16);
}
__device__ __forceinline__ float bf_lo(uint_t w) { return __uint_as_float(w << 16); }
__device__ __forceinline__ float bf_hi(uint_t w) { return __uint_as_float(w & 0xffff0000u); }

// ---------------- zero int scratch ----------------
__global__ void k_zero_i(int* __restrict__ p, int n) {
    int i = blockIdx.x * blockDim.x + threadIdx.x;
    if (i < n) p[i] = 0;
}

// ---------------- bucket scatter: packed edges into fixed-capacity buckets ----------------
// LDS-staged counting sort of each 8192-edge chunk: local hist -> local scan ->
// one global atomic per touched bucket (bkt_cnt is the cursor; bucket base is
// b<<CAPLOG) -> rank into bucket-major LDS staging -> linear coalesced write-out
// (runs avg ~21 edges; R9's per-thread cursors inflated HBM writes 3.5x).
__global__ __launch_bounds__(512) void k_bscatter(const int* __restrict__ ei, int E, int N,
                                                  int NBUK, int* __restrict__ bkt_cnt,
                                                  uint_t* __restrict__ ebuf) {
    __shared__ int hist[MAXBUK];
    __shared__ int loff[MAXBUK];     // local exclusive offsets; reused as rank cursor
    __shared__ int delta[MAXBUK];    // global_base - local_offset
    __shared__ int ssum[MAXBUK];
    __shared__ uint_t vals[SC_CHUNK];     // 32 KB
    __shared__ ushort_t buks[SC_CHUNK];   // 16 KB

    const int t = threadIdx.x;
    hist[t] = 0;
    __syncthreads();

    const int Etot = E + N;
    const int base0 = blockIdx.x * SC_CHUNK;
    const int lim = min(base0 + SC_CHUNK, Etot);
    const int cnt = lim - base0;

    uint_t myval[EPT];
    int myb[EPT];
#pragma unroll
    for (int i = 0; i < EPT; ++i) {
        int e = base0 + t + i * 512;
        if (e < lim) {
            int s, d;
            if (e < E) { s = ei[e]; d = ei[E + e]; } else { s = e - E; d = s; }
            myval[i] = ((uint_t)s << 8) | (uint_t)(d & 255);
            myb[i] = d >> 8;
            atomicAdd(&hist[myb[i]], 1);
        } else myb[i] = -1;
    }
    __syncthreads();

    // exclusive scan of hist[0..511] with 512 threads
    int v = hist[t];
    ssum[t] = v;
    __syncthreads();
    for (int o = 1; o < 512; o <<= 1) {
        int add = (t >= o) ? ssum[t - o] : 0;
        __syncthreads();
        ssum[t] += add;
        __syncthreads();
    }
    loff[t] = ssum[t] - v;   // exclusive
    __syncthreads();

    // global reservation: one atomic per touched bucket; base = b<<CAPLOG
    if (t < NBUK) {
        int c = hist[t];
        if (c) delta[t] = (t << CAPLOG) + atomicAdd(&bkt_cnt[t], c) - loff[t];
    }
    __syncthreads();

    // rank into staging (loff doubles as cursor; delta already captured)
#pragma unroll
    for (int i = 0; i < EPT; ++i) {
        if (myb[i] >= 0) {
            int pos = atomicAdd(&loff[myb[i]], 1);
            vals[pos] = myval[i];
            buks[pos] = (ushort_t)myb[i];
        }
    }
    __syncthreads();

    // linear write-out: consecutive i -> consecutive gaddr within each run
    for (int i = t; i < cnt; i += 512)
        ebuf[delta[buks[i]] + i] = vals[i];
}

// ---------------- per-bucket: degrees, offsets, and csr scatter ----------------
// One block (512 threads = 8 waves) per bucket. Count pass uses per-wave
// private histograms (8x less LDS-atomic contention), then 8-way reduce +
// scan; csr lives at fixed bucket stride so no cross-bucket scan anywhere.
__global__ __launch_bounds__(512) void k_bucket_csr(const uint_t* __restrict__ ebuf,
                                                    const int* __restrict__ bkt_cnt, int N,
                                                    int* __restrict__ deg, int* __restrict__ off,
                                                    int* __restrict__ csr) {
    __shared__ int degw[8 * 256];    // per-wave hists, 8 KB
    __shared__ int scan[256];
    __shared__ int curl[256];
    int b = blockIdx.x;
    int t = threadIdx.x;
    int wv = t >> 6;
    int beg = b << CAPLOG;
    int end = beg + bkt_cnt[b];
    for (int i = t; i < 8 * 256; i += 512) degw[i] = 0;
    __syncthreads();
    for (int j = beg + t; j < end; j += 512) {
        uint_t v = ebuf[j];
        atomicAdd(&degw[(wv << 8) + (v & 255u)], 1);
    }
    __syncthreads();
    int v = 0;
    if (t < 256) {
#pragma unroll
        for (int w = 0; w < 8; ++w) v += degw[(w << 8) + t];
        scan[t] = v;
    }
    __syncthreads();
    for (int o = 1; o < 256; o <<= 1) {
        int a = (t < 256 && t >= o) ? scan[t - o] : 0;
        __syncthreads();
        if (t < 256) scan[t] += a;
        __syncthreads();
    }
    if (t < 256) {
        int gpos = beg + scan[t] - v;
        int node = (b << 8) + t;
        if (node < N) { off[node] = gpos; deg[node] = v; }
        curl[t] = gpos;
    }
    __syncthreads();
    for (int j = beg + t; j < end; j += 512) {
        uint_t p = ebuf[j];
        int pos = atomicAdd(&curl[p & 255u], 1);
        csr[pos] = (int)(p >> 8);
    }
}

// ---------------- layer1 GEMM via MFMA + attention terms (bf16 outputs) ----------------
// h^T = W^T . x^T per mfma_f32_16x16x32_bf16 tile so D cols = nodes.
// 128 nodes/block (4 waves x 32 nodes): grid 782 -> ~3 blocks/CU.
// Outputs written SLICE-MAJOR for the 4-pass L2-resident aggregation:
//   h1t[slice][node][16]  (slice ct = heads 2ct,2ct+1)
//   as1t[slice][node] = packbf2(a_src[2ct], a_src[2ct+1])
//   ad1t[slice][node] = (a_dst[2ct], a_dst[2ct+1])
__global__ __launch_bounds__(256) void k_gemm1(
    const float* __restrict__ x, const float* __restrict__ W,
    const float* __restrict__ att_s, const float* __restrict__ att_d,
    ushort_t* __restrict__ h1t, uint_t* __restrict__ as1t, float2* __restrict__ ad1t, int N)
{
    __shared__ __align__(16) ushort_t Wt[C1 * WT_STRIDE];   // 33 KB

    const int t = threadIdx.x;
    {   // stage W^T bf16
        int c4 = t >> 4;
        int k0 = t & 15;
#pragma unroll
        for (int i = 0; i < 16; ++i) {
            int k = k0 + 16 * i;
            float4 v = *reinterpret_cast<const float4*>(&W[k * C1 + c4 * 4]);
            Wt[(c4 * 4 + 0) * WT_STRIDE + k] = f2bf(v.x);
            Wt[(c4 * 4 + 1) * WT_STRIDE + k] = f2bf(v.y);
            Wt[(c4 * 4 + 2) * WT_STRIDE + k] = f2bf(v.z);
            Wt[(c4 * 4 + 3) * WT_STRIDE + k] = f2bf(v.w);
        }
    }
    __syncthreads();

    const int wv = t >> 6, l = t & 63;
    const int l15 = l & 15, q = l >> 4;
    const int nodeBase = blockIdx.x * 128 + wv * 32;

    const float* xr[2];
#pragma unroll
    for (int nt = 0; nt < 2; ++nt) {
        int node = nodeBase + nt * 16 + l15;
        if (node >= N) node = N - 1;
        xr[nt] = x + (size_t)node * FIN;
    }

    f32x4 acc[4][2];   // [ct][nt]
#pragma unroll
    for (int ct = 0; ct < 4; ++ct)
#pragma unroll
        for (int nt = 0; nt < 2; ++nt)
            acc[ct][nt] = (f32x4){0.f, 0.f, 0.f, 0.f};

    for (int kk = 0; kk < 8; ++kk) {
        const int kof = kk * 32 + q * 8;
        short8 af[4];
#pragma unroll
        for (int ct = 0; ct < 4; ++ct)
            af[ct] = *reinterpret_cast<const short8*>(&Wt[(ct * 16 + l15) * WT_STRIDE + kof]);
#pragma unroll
        for (int nt = 0; nt < 2; ++nt) {
            const float4* xp = reinterpret_cast<const float4*>(xr[nt] + kof);
            float4 v0 = xp[0], v1 = xp[1];
            union { short8 s; uint_t u[4]; } bu;
            bu.u[0] = packbf2(v0.x, v0.y);
            bu.u[1] = packbf2(v0.z, v0.w);
            bu.u[2] = packbf2(v1.x, v1.y);
            bu.u[3] = packbf2(v1.z, v1.w);
#pragma unroll
            for (int ct = 0; ct < 4; ++ct)
                acc[ct][nt] = __builtin_amdgcn_mfma_f32_16x16x32_bf16(
                    af[ct], bu.s, acc[ct][nt], 0, 0, 0);
        }
    }

    float4 ats[4], atd4[4];
#pragma unroll
    for (int ct = 0; ct < 4; ++ct) {
        ats[ct]  = *reinterpret_cast<const float4*>(&att_s[ct * 16 + q * 4]);
        atd4[ct] = *reinterpret_cast<const float4*>(&att_d[ct * 16 + q * 4]);
    }
    const int hb = q >> 1;

#pragma unroll
    for (int nt = 0; nt < 2; ++nt) {
        int node = nodeBase + nt * 16 + l15;
        bool ok = node < N;
        float asp[8], adp[8];
#pragma unroll
        for (int h = 0; h < 8; ++h) { asp[h] = 0.f; adp[h] = 0.f; }
#pragma unroll
        for (int ct = 0; ct < 4; ++ct) {
            f32x4 a = acc[ct][nt];
            if (ok) {
                uint2 hv;
                hv.x = packbf2(a[0], a[1]);
                hv.y = packbf2(a[2], a[3]);
                *reinterpret_cast<uint2*>(&h1t[((size_t)ct * N + node) * 16 + q * 4]) = hv;
            }
            int h = ct * 2 + hb;
            asp[h] = a[0] * ats[ct].x + a[1] * ats[ct].y + a[2] * ats[ct].z + a[3] * ats[ct].w;
            adp[h] = a[0] * atd4[ct].x + a[1] * atd4[ct].y + a[2] * atd4[ct].z + a[3] * atd4[ct].w;
        }
#pragma unroll
        for (int o = 16; o <= 32; o <<= 1) {
#pragma unroll
            for (int h = 0; h < 8; ++h) {
                asp[h] += __shfl_xor(asp[h], o, 64);
                adp[h] += __shfl_xor(adp[h], o, 64);
            }
        }
        if (q == 0 && ok) {
#pragma unroll
            for (int hh = 0; hh < 4; ++hh) {
                as1t[(size_t)hh * N + node] = packbf2(asp[2 * hh], asp[2 * hh + 1]);
                ad1t[(size_t)hh * N + node] = make_float2(adp[2 * hh], adp[2 * hh + 1]);
            }
        }
    }
}

// ---------------- layer1 aggregation pass: one 16-feature slice (2 heads) ----------------
// 16 lanes/node, each lane owns edges strided 16. Per-pass gather working set
// (h1 slice 3.2MB + as1t slice 0.4MB) fits the 4MB per-XCD L2, so the per-edge
// 36B gather is an L2 hit instead of the old 3.1 TB/s scattered L3 fill.
// Partial W2 projection (incl. bias + ELU, legal since a slice = 2 whole heads
// and softmax denoms are per-head) accumulates into h2 across the 4 launches.
__global__ __launch_bounds__(256) void k_agg1p(
    const int* __restrict__ csr, const int* __restrict__ off, const int* __restrict__ deg,
    const uint_t* __restrict__ as1s, const float2* __restrict__ ad1s,
    const ushort_t* __restrict__ h1s,
    const float* __restrict__ b1s, const float* __restrict__ W2s,
    float* __restrict__ h2, int N, int first)
{
    int idx = blockIdx.x * 256 + threadIdx.x;
    int n = idx >> 4;
    if (n >= N) return;
    int sub = threadIdx.x & 15;

    int beg = off[n];
    int end = beg + deg[n];

    float2 adv = ad1s[n];
    float den0 = 0.f, den1 = 0.f;
    float acc[16];
#pragma unroll
    for (int k = 0; k < 16; ++k) acc[k] = 0.f;

    for (int j = beg + sub; j < end; j += 16) {
        int s = csr[j];
        uint_t a2 = as1s[s];
        float t0 = bf_lo(a2) + adv.x;
        float t1 = bf_hi(a2) + adv.y;
        t0 = fmaxf(t0, 0.2f * t0);
        t1 = fmaxf(t1, 0.2f * t1);
        float ex0 = __expf(t0);
        float ex1 = __expf(t1);
        den0 += ex0; den1 += ex1;
        const uint4* hbp = reinterpret_cast<const uint4*>(h1s + (size_t)s * 16);
        uint4 u0 = hbp[0], u1 = hbp[1];
        acc[0]  = fmaf(ex0, bf_lo(u0.x), acc[0]);
        acc[1]  = fmaf(ex0, bf_hi(u0.x), acc[1]);
        acc[2]  = fmaf(ex0, bf_lo(u0.y), acc[2]);
        acc[3]  = fmaf(ex0, bf_hi(u0.y), acc[3]);
        acc[4]  = fmaf(ex0, bf_lo(u0.z), acc[4]);
        acc[5]  = fmaf(ex0, bf_hi(u0.z), acc[5]);
        acc[6]  = fmaf(ex0, bf_lo(u0.w), acc[6]);
        acc[7]  = fmaf(ex0, bf_hi(u0.w), acc[7]);
        acc[8]  = fmaf(ex1, bf_lo(u1.x), acc[8]);
        acc[9]  = fmaf(ex1, bf_hi(u1.x), acc[9]);
        acc[10] = fmaf(ex1, bf_lo(u1.y), acc[10]);
        acc[11] = fmaf(ex1, bf_hi(u1.y), acc[11]);
        acc[12] = fmaf(ex1, bf_lo(u1.z), acc[12]);
        acc[13] = fmaf(ex1, bf_hi(u1.z), acc[13]);
        acc[14] = fmaf(ex1, bf_hi(u1.w) * 0.f + bf_lo(u1.w), acc[14]);
        acc[15] = fmaf(ex1, bf_hi(u1.w), acc[15]);
    }

#pragma unroll
    for (int o = 1; o <= 8; o <<= 1) {
        den0 += __shfl_xor(den0, o, 64);
        den1 += __shfl_xor(den1, o, 64);
#pragma unroll
        for (int k = 0; k < 16; ++k) acc[k] += __shfl_xor(acc[k], o, 64);
    }

    if (sub == 0) {
        float inv0 = 1.f / (den0 + 1e-16f);
        float inv1 = 1.f / (den1 + 1e-16f);
        float p = 0.f;
#pragma unroll
        for (int k = 0; k < 16; ++k) {
            float inv = (k < 8) ? inv0 : inv1;
            float v = acc[k] * inv + b1s[k];
            v = v > 0.f ? v : (__expf(v) - 1.f);  // ELU, fast path
            p = fmaf(v, W2s[k], p);
        }
        h2[n] = (first ? 0.f : h2[n]) + p;
    }
}

// ---------------- fused layer2: softmax + aggregate + bias + sigmoid ----------------
__global__ __launch_bounds__(256) void k_agg2(
    const int* __restrict__ csr, const int* __restrict__ off, const int* __restrict__ deg,
    const float* __restrict__ h2,
    const float* __restrict__ ats2, const float* __restrict__ atd2,
    const float* __restrict__ b2, float* __restrict__ out, int N)
{
    int idx = blockIdx.x * 256 + threadIdx.x;
    int n = idx >> 4;
    int l16 = threadIdx.x & 15;
    if (n >= N) return;
    int beg = off[n];
    int end = beg + deg[n];
    float a_s = ats2[0], a_d = atd2[0];
    float adv = h2[n] * a_d;
    float den = 0.f, num = 0.f;
    for (int j = beg + l16; j < end; j += 16) {
        float hs = h2[csr[j]];
        float t = fmaf(hs, a_s, adv);
        t = fmaxf(t, 0.2f * t);
        float ex = __expf(t);
        den += ex;
        num = fmaf(ex, hs, num);
    }
#pragma unroll
    for (int o = 1; o <= 8; o <<= 1) {
        den += __shfl_xor(den, o, 64);
        num += __shfl_xor(num, o, 64);
    }
    if (l16 == 0) {
        float t = num / (den + 1e-16f) + b2[0];
        out[n] = 1.f / (1.f + __expf(-t));
    }
}

extern "C" void kernel_launch(void* const* d_in, const int* in_sizes, int n_in,
                              void* d_out, int out_size, void* d_ws, size_t ws_size,
                              hipStream_t stream)
{
    const float* x    = (const float*)d_in[0];
    const int*   ei   = (const int*)d_in[1];
    const float* W1   = (const float*)d_in[2];
    const float* ats1 = (const float*)d_in[3];
    const float* atd1 = (const float*)d_in[4];
    const float* b1   = (const float*)d_in[5];
    const float* W2   = (const float*)d_in[6];
    const float* ats2 = (const float*)d_in[7];
    const float* atd2 = (const float*)d_in[8];
    const float* b2   = (const float*)d_in[9];
    float* out = (float*)d_out;

    const int N = out_size;            // 100000
    const int E = in_sizes[1] / 2;     // 3200000
    const int Etot = E + N;
    const int NBUK = (N + 255) >> 8;   // 391 (<= MAXBUK)
    const size_t capElems = (size_t)NBUK << CAPLOG;   // 6.4M slots (25.6 MB)

    // workspace layout:
    //   union region: ebuf uint[NBUK<<CAPLOG] (25.6MB)  OVERLAYS  feature block
    //                 {h1t bf16[4][N][16], as1t uint[4][N], ad1t float2[4][N],
    //                  h2 f32[N]} (18MB)
    //   then ints: deg[N] off[N] bkt_cnt[512] csr[NBUK<<CAPLOG]
    char* base = (char*)d_ws;
    uint_t* ebuf = (uint_t*)base;
    ushort_t* h1t  = (ushort_t*)base;                       // 4*N*16 bf16 = 12.8MB
    uint_t* as1t   = (uint_t*)(h1t + (size_t)N * C1);       // 4*N uint  = 1.6MB
    float2* ad1t   = (float2*)(as1t + (size_t)N * 4);       // 4*N f32x2 = 3.2MB
    float* h2      = (float*)(ad1t + (size_t)N * 4);        // N f32
    size_t featBytes = (size_t)N * (C1 * 2 + 4 * 4 + 4 * 8 + 4);
    size_t unionBytes = capElems * sizeof(uint_t);
    if (featBytes > unionBytes) unionBytes = featBytes;
    unionBytes = (unionBytes + 255) & ~(size_t)255;
    int* deg     = (int*)(base + unionBytes);
    int* off     = deg + N;
    int* bkt_cnt = off + N;
    int* csr     = bkt_cnt + MAXBUK;

    k_zero_i<<<2, 256, 0, stream>>>(bkt_cnt, MAXBUK);
    k_bscatter<<<(Etot + SC_CHUNK - 1) / SC_CHUNK, 512, 0, stream>>>(ei, E, N, NBUK, bkt_cnt, ebuf);
    k_bucket_csr<<<NBUK, 512, 0, stream>>>(ebuf, bkt_cnt, N, deg, off, csr);

    k_gemm1<<<(N + 127) / 128, 256, 0, stream>>>(x, W1, ats1, atd1, h1t, as1t, ad1t, N);
    for (int hp = 0; hp < 4; ++hp) {
        k_agg1p<<<(N * 16 + 255) / 256, 256, 0, stream>>>(
            csr, off, deg,
            as1t + (size_t)hp * N,
            ad1t + (size_t)hp * N,
            h1t + (size_t)hp * N * 16,
            b1 + hp * 16, W2 + hp * 16,
            h2, N, hp == 0 ? 1 : 0);
    }
    k_agg2<<<(N * 16 + 255) / 256, 256, 0, stream>>>(csr, off, deg, h2, ats2, atd2, b2, out, N);
}

// Round 2
// 331.193 us; speedup vs baseline: 1.2485x; 1.2485x over previous
//
#include <hip/hip_runtime.h>
#include <math.h>

// GAT 2-layer pipeline. CSR-by-dst built per launch via LDS-staged counting
// sort into FIXED-CAPACITY buckets (16384 slots/bucket; bucket load is
// Binomial(3.3M,1/391): mean 8448, sigma 92 -> cap is +86 sigma, unreachable).
// Aggregation: atomic-free per-node online softmax, bf16 features (absmax
// ~4e-3 << 1.1e-2 threshold). Layer-1 GEMM on MFMA (bf16): h^T = W^T . x^T.
// Sizes fixed by reference: F_IN=256, HEADS=8, HID=8 -> C1=64; layer2 1x1.
//
// R2: (a) REVERT the R1 4-pass feature-sliced aggregation (each pass was
// latency-bound at ~2 loop iters/lane + 4x csr re-read + 4x shuffle reduce;
// sum ~150us vs 73us single-pass). (b) k_gemm1 was exposed as the #2 kernel
// (62us, Occupancy 23%, all pipes idle -> latency-bound, grid 782 + 33KB LDS).
// Fix: W pre-transposed to a GLOBAL bf16 Wt[64][256] table (32KB, L1/L2
// resident) by k_prep; k_gemm1 has NO LDS, 64 nodes/block -> grid 1563,
// ~6 blocks/CU * 4 waves = ~75% occupancy ceiling, no staging prologue.
#define FIN 256
#define C1  64
#define NH  8
#define HID 8
#define MAXBUK 512        // buckets of 256 nodes; N=100000 -> 391 buckets
#define CAPLOG 14         // fixed bucket capacity 16384 edges
#define SC_CHUNK 8192     // edges per k_bscatter block (512 thr, EPT 16)
#define EPT (SC_CHUNK / 512)

typedef unsigned short ushort_t;
typedef unsigned int uint_t;
typedef __attribute__((ext_vector_type(8))) short short8;   // 8 x bf16 MFMA frag
typedef __attribute__((ext_vector_type(4))) float f32x4;    // MFMA acc

__device__ __forceinline__ ushort_t f2bf(float f) {   // round-to-nearest-even
    uint_t u = __float_as_uint(f);
    u += 0x7fffu + ((u >> 16) & 1u);
    return (ushort_t)(u >> 16);
}
__device__ __forceinline__ uint_t packbf2(float lo, float hi) {
    return (uint_t)f2bf(lo) | ((uint_t)f2bf(hi) << 16);
}
__device__ __forceinline__ float bf_lo(uint_t w) { return __uint_as_float(w << 16); }
__device__ __forceinline__ float bf_hi(uint_t w) { return __uint_as_float(w & 0xffff0000u); }

// ---------------- prep: zero bkt_cnt + transpose W -> global bf16 Wt[64][256] ----------------
// grid 64 x 256 = 16384 threads = one per Wt element. Writes coalesced
// (consecutive k per lane); W reads are strided but total only 64KB.
__global__ void k_prep(const float* __restrict__ W, ushort_t* __restrict__ Wtg,
                       int* __restrict__ bkt_cnt) {
    int tid = blockIdx.x * 256 + threadIdx.x;
    if (tid < MAXBUK) bkt_cnt[tid] = 0;
    int c = tid >> 8;        // 0..63
    int k = tid & 255;       // 0..255
    Wtg[c * 256 + k] = f2bf(W[k * C1 + c]);
}

// ---------------- bucket scatter: packed edges into fixed-capacity buckets ----------------
// LDS-staged counting sort of each 8192-edge chunk: local hist -> local scan ->
// one global atomic per touched bucket (bkt_cnt is the cursor; bucket base is
// b<<CAPLOG) -> rank into bucket-major LDS staging -> linear coalesced write-out
// (runs avg ~21 edges; R9's per-thread cursors inflated HBM writes 3.5x).
__global__ __launch_bounds__(512) void k_bscatter(const int* __restrict__ ei, int E, int N,
                                                  int NBUK, int* __restrict__ bkt_cnt,
                                                  uint_t* __restrict__ ebuf) {
    __shared__ int hist[MAXBUK];
    __shared__ int loff[MAXBUK];     // local exclusive offsets; reused as rank cursor
    __shared__ int delta[MAXBUK];    // global_base - local_offset
    __shared__ int ssum[MAXBUK];
    __shared__ uint_t vals[SC_CHUNK];     // 32 KB
    __shared__ ushort_t buks[SC_CHUNK];   // 16 KB

    const int t = threadIdx.x;
    hist[t] = 0;
    __syncthreads();

    const int Etot = E + N;
    const int base0 = blockIdx.x * SC_CHUNK;
    const int lim = min(base0 + SC_CHUNK, Etot);
    const int cnt = lim - base0;

    uint_t myval[EPT];
    int myb[EPT];
#pragma unroll
    for (int i = 0; i < EPT; ++i) {
        int e = base0 + t + i * 512;
        if (e < lim) {
            int s, d;
            if (e < E) { s = ei[e]; d = ei[E + e]; } else { s = e - E; d = s; }
            myval[i] = ((uint_t)s << 8) | (uint_t)(d & 255);
            myb[i] = d >> 8;
            atomicAdd(&hist[myb[i]], 1);
        } else myb[i] = -1;
    }
    __syncthreads();

    // exclusive scan of hist[0..511] with 512 threads
    int v = hist[t];
    ssum[t] = v;
    __syncthreads();
    for (int o = 1; o < 512; o <<= 1) {
        int add = (t >= o) ? ssum[t - o] : 0;
        __syncthreads();
        ssum[t] += add;
        __syncthreads();
    }
    loff[t] = ssum[t] - v;   // exclusive
    __syncthreads();

    // global reservation: one atomic per touched bucket; base = b<<CAPLOG
    if (t < NBUK) {
        int c = hist[t];
        if (c) delta[t] = (t << CAPLOG) + atomicAdd(&bkt_cnt[t], c) - loff[t];
    }
    __syncthreads();

    // rank into staging (loff doubles as cursor; delta already captured)
#pragma unroll
    for (int i = 0; i < EPT; ++i) {
        if (myb[i] >= 0) {
            int pos = atomicAdd(&loff[myb[i]], 1);
            vals[pos] = myval[i];
            buks[pos] = (ushort_t)myb[i];
        }
    }
    __syncthreads();

    // linear write-out: consecutive i -> consecutive gaddr within each run
    for (int i = t; i < cnt; i += 512)
        ebuf[delta[buks[i]] + i] = vals[i];
}

// ---------------- per-bucket: degrees, offsets, and csr scatter ----------------
// One block (512 threads = 8 waves) per bucket. Count pass uses per-wave
// private histograms (8x less LDS-atomic contention), then 8-way reduce +
// scan; csr lives at fixed bucket stride so no cross-bucket scan anywhere.
__global__ __launch_bounds__(512) void k_bucket_csr(const uint_t* __restrict__ ebuf,
                                                    const int* __restrict__ bkt_cnt, int N,
                                                    int* __restrict__ deg, int* __restrict__ off,
                                                    int* __restrict__ csr) {
    __shared__ int degw[8 * 256];    // per-wave hists, 8 KB
    __shared__ int scan[256];
    __shared__ int curl[256];
    int b = blockIdx.x;
    int t = threadIdx.x;
    int wv = t >> 6;
    int beg = b << CAPLOG;
    int end = beg + bkt_cnt[b];
    for (int i = t; i < 8 * 256; i += 512) degw[i] = 0;
    __syncthreads();
    for (int j = beg + t; j < end; j += 512) {
        uint_t v = ebuf[j];
        atomicAdd(&degw[(wv << 8) + (v & 255u)], 1);
    }
    __syncthreads();
    int v = 0;
    if (t < 256) {
#pragma unroll
        for (int w = 0; w < 8; ++w) v += degw[(w << 8) + t];
        scan[t] = v;
    }
    __syncthreads();
    for (int o = 1; o < 256; o <<= 1) {
        int a = (t < 256 && t >= o) ? scan[t - o] : 0;
        __syncthreads();
        if (t < 256) scan[t] += a;
        __syncthreads();
    }
    if (t < 256) {
        int gpos = beg + scan[t] - v;
        int node = (b << 8) + t;
        if (node < N) { off[node] = gpos; deg[node] = v; }
        curl[t] = gpos;
    }
    __syncthreads();
    for (int j = beg + t; j < end; j += 512) {
        uint_t p = ebuf[j];
        int pos = atomicAdd(&curl[p & 255u], 1);
        csr[pos] = (int)(p >> 8);
    }
}

// ---------------- layer1 GEMM via MFMA + attention terms (bf16 outputs) ----------------
// h^T = W^T . x^T per mfma_f32_16x16x32_bf16 tile so D cols = nodes.
// NO LDS: A-fragments read from global bf16 Wt[64][256] (32KB, L1/L2
// resident, same addresses repeat across every wave). 64 nodes/block
// (4 waves x 16 nodes) -> grid 1563 -> ~6 blocks/CU, occupancy ~75%.
__global__ __launch_bounds__(256) void k_gemm1(
    const float* __restrict__ x, const ushort_t* __restrict__ Wtg,
    const float* __restrict__ att_s, const float* __restrict__ att_d,
    ushort_t* __restrict__ h1b, ushort_t* __restrict__ as1b, float* __restrict__ ad1, int N)
{
    const int t = threadIdx.x;
    const int wv = t >> 6, l = t & 63;
    const int l15 = l & 15, q = l >> 4;
    const int node = blockIdx.x * 64 + wv * 16 + l15;
    const bool ok = node < N;
    const float* xr = x + (size_t)(ok ? node : N - 1) * FIN;

    f32x4 acc[4];   // [ct] : output channels ct*16 + q*4 + 0..3, col = node
#pragma unroll
    for (int ct = 0; ct < 4; ++ct) acc[ct] = (f32x4){0.f, 0.f, 0.f, 0.f};

    for (int kk = 0; kk < 8; ++kk) {
        const int kof = kk * 32 + q * 8;
        short8 af[4];
#pragma unroll
        for (int ct = 0; ct < 4; ++ct)
            af[ct] = *reinterpret_cast<const short8*>(&Wtg[(ct * 16 + l15) * 256 + kof]);
        const float4* xp = reinterpret_cast<const float4*>(xr + kof);
        float4 v0 = xp[0], v1 = xp[1];
        union { short8 s; uint_t u[4]; } bu;
        bu.u[0] = packbf2(v0.x, v0.y);
        bu.u[1] = packbf2(v0.z, v0.w);
        bu.u[2] = packbf2(v1.x, v1.y);
        bu.u[3] = packbf2(v1.z, v1.w);
#pragma unroll
        for (int ct = 0; ct < 4; ++ct)
            acc[ct] = __builtin_amdgcn_mfma_f32_16x16x32_bf16(af[ct], bu.s, acc[ct], 0, 0, 0);
    }

    float4 ats[4], atd4[4];
#pragma unroll
    for (int ct = 0; ct < 4; ++ct) {
        ats[ct]  = *reinterpret_cast<const float4*>(&att_s[ct * 16 + q * 4]);
        atd4[ct] = *reinterpret_cast<const float4*>(&att_d[ct * 16 + q * 4]);
    }
    const int hb = q >> 1;

    float asp[8], adp[8];
#pragma unroll
    for (int h = 0; h < 8; ++h) { asp[h] = 0.f; adp[h] = 0.f; }
#pragma unroll
    for (int ct = 0; ct < 4; ++ct) {
        f32x4 a = acc[ct];
        if (ok) {
            uint2 hv;
            hv.x = packbf2(a[0], a[1]);
            hv.y = packbf2(a[2], a[3]);
            *reinterpret_cast<uint2*>(&h1b[(size_t)node * C1 + ct * 16 + q * 4]) = hv;
        }
        int h = ct * 2 + hb;
        asp[h] = a[0] * ats[ct].x + a[1] * ats[ct].y + a[2] * ats[ct].z + a[3] * ats[ct].w;
        adp[h] = a[0] * atd4[ct].x + a[1] * atd4[ct].y + a[2] * atd4[ct].z + a[3] * atd4[ct].w;
    }
#pragma unroll
    for (int o = 16; o <= 32; o <<= 1) {
#pragma unroll
        for (int h = 0; h < 8; ++h) {
            asp[h] += __shfl_xor(asp[h], o, 64);
            adp[h] += __shfl_xor(adp[h], o, 64);
        }
    }
    if (q == 0 && ok) {
        uint4 aw;
        aw.x = packbf2(asp[0], asp[1]);
        aw.y = packbf2(asp[2], asp[3]);
        aw.z = packbf2(asp[4], asp[5]);
        aw.w = packbf2(asp[6], asp[7]);
        *reinterpret_cast<uint4*>(&as1b[(size_t)node * NH]) = aw;
        *reinterpret_cast<float4*>(&ad1[(size_t)node * NH]) =
            make_float4(adp[0], adp[1], adp[2], adp[3]);
        *reinterpret_cast<float4*>(&ad1[(size_t)node * NH + 4]) =
            make_float4(adp[4], adp[5], adp[6], adp[7]);
    }
}

// ---------------- fused layer1 aggregation + bias/ELU + W2 projection ----------------
// 4 nodes per wave, 16 lanes/node: sub = lane&15, slot = sub>>2, hp = sub&3.
// Structural limit: 224MB L2-miss gather traffic at the ~3.1 TB/s scattered
// 64B-line L3->L2 rate; fp8 would halve bytes but busts the error budget.
__global__ __launch_bounds__(256) void k_agg1(
    const int* __restrict__ csr, const int* __restrict__ off, const int* __restrict__ deg,
    const ushort_t* __restrict__ as1b, const float* __restrict__ ad1,
    const ushort_t* __restrict__ h1b,
    const float* __restrict__ b1, const float* __restrict__ W2,
    float* __restrict__ h2, int N)
{
    int idx = blockIdx.x * 256 + threadIdx.x;
    int n = idx >> 4;
    if (n >= N) return;
    int sub  = threadIdx.x & 15;
    int hp   = sub & 3;
    int slot = sub >> 2;

    int beg = off[n];
    int end = beg + deg[n];

    float adv0 = ad1[(size_t)n * NH + 2 * hp];
    float adv1 = ad1[(size_t)n * NH + 2 * hp + 1];
    float den0 = 0.f, den1 = 0.f;
    float acc[16];
#pragma unroll
    for (int k = 0; k < 16; ++k) acc[k] = 0.f;

    for (int base = beg; base < end; base += 4) {
        int j = base + slot;
        int jj = j < end ? j : end - 1;
        int s = csr[jj];
        uint_t a2 = *reinterpret_cast<const uint_t*>(&as1b[(size_t)s * NH + 2 * hp]);
        float t0 = bf_lo(a2) + adv0;
        float t1 = bf_hi(a2) + adv1;
        t0 = fmaxf(t0, 0.2f * t0);
        t1 = fmaxf(t1, 0.2f * t1);
        bool live = j < end;
        float ex0 = live ? __expf(t0) : 0.f;
        float ex1 = live ? __expf(t1) : 0.f;
        den0 += ex0; den1 += ex1;
        const uint4* hbp = reinterpret_cast<const uint4*>(&h1b[(size_t)s * C1 + hp * 16]);
        uint4 u0 = hbp[0], u1 = hbp[1];
        acc[0]  = fmaf(ex0, bf_lo(u0.x), acc[0]);
        acc[1]  = fmaf(ex0, bf_hi(u0.x), acc[1]);
        acc[2]  = fmaf(ex0, bf_lo(u0.y), acc[2]);
        acc[3]  = fmaf(ex0, bf_hi(u0.y), acc[3]);
        acc[4]  = fmaf(ex0, bf_lo(u0.z), acc[4]);
        acc[5]  = fmaf(ex0, bf_hi(u0.z), acc[5]);
        acc[6]  = fmaf(ex0, bf_lo(u0.w), acc[6]);
        acc[7]  = fmaf(ex0, bf_hi(u0.w), acc[7]);
        acc[8]  = fmaf(ex1, bf_lo(u1.x), acc[8]);
        acc[9]  = fmaf(ex1, bf_hi(u1.x), acc[9]);
        acc[10] = fmaf(ex1, bf_lo(u1.y), acc[10]);
        acc[11] = fmaf(ex1, bf_hi(u1.y), acc[11]);
        acc[12] = fmaf(ex1, bf_lo(u1.z), acc[12]);
        acc[13] = fmaf(ex1, bf_hi(u1.z), acc[13]);
        acc[14] = fmaf(ex1, bf_lo(u1.w), acc[14]);
        acc[15] = fmaf(ex1, bf_hi(u1.w), acc[15]);
    }

#pragma unroll
    for (int o = 4; o <= 8; o <<= 1) {
        den0 += __shfl_xor(den0, o, 64);
        den1 += __shfl_xor(den1, o, 64);
#pragma unroll
        for (int k = 0; k < 16; ++k) acc[k] += __shfl_xor(acc[k], o, 64);
    }

    float inv0 = 1.f / (den0 + 1e-16f);
    float inv1 = 1.f / (den1 + 1e-16f);
    const float4* bp = reinterpret_cast<const float4*>(&b1[hp * 16]);
    const float4* wp = reinterpret_cast<const float4*>(&W2[hp * 16]);
    float bb[16], ww[16];
#pragma unroll
    for (int i = 0; i < 4; ++i) {
        float4 b4 = bp[i], w4 = wp[i];
        bb[4 * i] = b4.x; bb[4 * i + 1] = b4.y; bb[4 * i + 2] = b4.z; bb[4 * i + 3] = b4.w;
        ww[4 * i] = w4.x; ww[4 * i + 1] = w4.y; ww[4 * i + 2] = w4.z; ww[4 * i + 3] = w4.w;
    }
    float p = 0.f;
#pragma unroll
    for (int k = 0; k < 16; ++k) {
        float inv = (k < 8) ? inv0 : inv1;
        float v = acc[k] * inv + bb[k];
        v = v > 0.f ? v : (__expf(v) - 1.f);  // ELU, fast path
        p = fmaf(v, ww[k], p);
    }
#pragma unroll
    for (int o = 1; o <= 2; o <<= 1) p += __shfl_xor(p, o, 64);
    if (sub == 0) h2[n] = p;
}

// ---------------- fused layer2: softmax + aggregate + bias + sigmoid ----------------
__global__ __launch_bounds__(256) void k_agg2(
    const int* __restrict__ csr, const int* __restrict__ off, const int* __restrict__ deg,
    const float* __restrict__ h2,
    const float* __restrict__ ats2, const float* __restrict__ atd2,
    const float* __restrict__ b2, float* __restrict__ out, int N)
{
    int idx = blockIdx.x * 256 + threadIdx.x;
    int n = idx >> 4;
    int l16 = threadIdx.x & 15;
    if (n >= N) return;
    int beg = off[n];
    int end = beg + deg[n];
    float a_s = ats2[0], a_d = atd2[0];
    float adv = h2[n] * a_d;
    float den = 0.f, num = 0.f;
    for (int j = beg + l16; j < end; j += 16) {
        float hs = h2[csr[j]];
        float t = fmaf(hs, a_s, adv);
        t = fmaxf(t, 0.2f * t);
        float ex = __expf(t);
        den += ex;
        num = fmaf(ex, hs, num);
    }
#pragma unroll
    for (int o = 1; o <= 8; o <<= 1) {
        den += __shfl_xor(den, o, 64);
        num += __shfl_xor(num, o, 64);
    }
    if (l16 == 0) {
        float t = num / (den + 1e-16f) + b2[0];
        out[n] = 1.f / (1.f + __expf(-t));
    }
}

extern "C" void kernel_launch(void* const* d_in, const int* in_sizes, int n_in,
                              void* d_out, int out_size, void* d_ws, size_t ws_size,
                              hipStream_t stream)
{
    const float* x    = (const float*)d_in[0];
    const int*   ei   = (const int*)d_in[1];
    const float* W1   = (const float*)d_in[2];
    const float* ats1 = (const float*)d_in[3];
    const float* atd1 = (const float*)d_in[4];
    const float* b1   = (const float*)d_in[5];
    const float* W2   = (const float*)d_in[6];
    const float* ats2 = (const float*)d_in[7];
    const float* atd2 = (const float*)d_in[8];
    const float* b2   = (const float*)d_in[9];
    float* out = (float*)d_out;

    const int N = out_size;            // 100000
    const int E = in_sizes[1] / 2;     // 3200000
    const int Etot = E + N;
    const int NBUK = (N + 255) >> 8;   // 391 (<= MAXBUK)
    const size_t capElems = (size_t)NBUK << CAPLOG;   // 6.4M slots (25.6 MB)

    // workspace layout:
    //   union region: ebuf uint[NBUK<<CAPLOG] (25.6MB)  OVERLAYS  feature block
    //                 {h1b bf16[N*64], as1b bf16[N*8], ad1 f32[N*8], h2 f32[N]} (18MB)
    //   then ints: deg[N] off[N] bkt_cnt[512] csr[NBUK<<CAPLOG]  then Wt bf16[64*256]
    char* base = (char*)d_ws;
    uint_t* ebuf = (uint_t*)base;
    ushort_t* h1b  = (ushort_t*)base;
    ushort_t* as1b = h1b + (size_t)N * C1;
    float* ad1 = (float*)(as1b + (size_t)N * NH);
    float* h2  = ad1 + (size_t)N * NH;
    size_t featBytes = (size_t)N * (C1 * 2 + NH * 2 + NH * 4 + 4);
    size_t unionBytes = capElems * sizeof(uint_t);
    if (featBytes > unionBytes) unionBytes = featBytes;
    unionBytes = (unionBytes + 255) & ~(size_t)255;
    int* deg     = (int*)(base + unionBytes);
    int* off     = deg + N;
    int* bkt_cnt = off + N;
    int* csr     = bkt_cnt + MAXBUK;
    ushort_t* wtg = (ushort_t*)(csr + capElems);   // 32 KB global Wt

    k_prep<<<64, 256, 0, stream>>>(W1, wtg, bkt_cnt);
    k_bscatter<<<(Etot + SC_CHUNK - 1) / SC_CHUNK, 512, 0, stream>>>(ei, E, N, NBUK, bkt_cnt, ebuf);
    k_bucket_csr<<<NBUK, 512, 0, stream>>>(ebuf, bkt_cnt, N, deg, off, csr);

    k_gemm1<<<(N + 63) / 64, 256, 0, stream>>>(x, wtg, ats1, atd1, h1b, as1b, ad1, N);
    k_agg1<<<(N * 16 + 255) / 256, 256, 0, stream>>>(csr, off, deg, as1b, ad1, h1b, b1, W2, h2, N);
    k_agg2<<<(N * 16 + 255) / 256, 256, 0, stream>>>(csr, off, deg, h2, ats2, atd2, b2, out, N);
}